// Round 5
// baseline (745.490 us; speedup 1.0000x reference)
//
#include <hip/hip_runtime.h>

#define BATCH 2048
#define CIN   512
#define COUT  512
#define GSZ   24
#define NORB  24
#define M_DIM (BATCH*GSZ)   // 49152
#define K_DIM (GSZ*CIN)     // 12288
#define N_DIM COUT          // 512
#define BM 192              // = 8 whole batches -> batch-aligned tiles
#define BN 128
#define BK 32               // R4: halved -> LDS 39KB -> 4 blocks/CU (16 waves)

typedef __bf16 bf16x8 __attribute__((ext_vector_type(8)));
typedef float  f32x4  __attribute__((ext_vector_type(4)));
typedef unsigned short u16;

__device__ __forceinline__ u16 f2bf(float f) {
  union { float f; unsigned u; } v; v.f = f;
  unsigned u = v.u;
  return (u16)((u + 0x7fffu + ((u >> 16) & 1u)) >> 16);  // RNE
}

// ---- pre-pass 1: x fp32 -> bf16 (coalesced both ways, 4 float4/thread) ----
__global__ void convert_x(const float* __restrict__ x, u16* __restrict__ xb, int n4) {
  const int base = blockIdx.x * 1024 + threadIdx.x;
#pragma unroll
  for (int i = 0; i < 4; ++i) {
    const int t = base + i * 256;
    if (t >= n4) return;
    const float4 v = *(const float4*)(x + (size_t)t * 4);
    ushort4 o;
    o.x = f2bf(v.x); o.y = f2bf(v.y); o.z = f2bf(v.z); o.w = f2bf(v.w);
    *(ushort4*)(xb + (size_t)t * 4) = o;
  }
}

// ---- pre-pass 2: weight (O,C,R) fp32 -> Bt[o][r*512+c] bf16 ----
#define TROW 520
__global__ void build_bt(const float* __restrict__ w, u16* __restrict__ bt) {
  __shared__ __align__(16) u16 lds[NORB * TROW];
  const int o = blockIdx.x;
  const int t = threadIdx.x;
  const float* wo = w + (size_t)o * K_DIM;
#pragma unroll
  for (int it = 0; it < 12; ++it) {
    const int idx = it * 256 + t;
    const float4 v = *(const float4*)(wo + idx * 4);
    const int k0 = idx * 4;
#pragma unroll
    for (int e = 0; e < 4; ++e) {
      const int k = k0 + e;
      const int c = k / 24;
      const int r = k - c * 24;
      lds[r * TROW + c] = f2bf(e == 0 ? v.x : e == 1 ? v.y : e == 2 ? v.z : v.w);
    }
  }
  __syncthreads();
  u16* bo = bt + (size_t)o * K_DIM;
#pragma unroll
  for (int it = 0; it < 6; ++it) {
    const int eidx = it * 256 + t;
    const int base = eidx * 8;
    const int r = base >> 9;
    const int c0 = base & 511;
    const uint4 v = *(const uint4*)(lds + r * TROW + c0);
    *(uint4*)(bo + base) = v;
  }
}

// ---- main GEMM: C[M,512] = A[M,K] * B[K,512] + bias ----
// R1/R3 structure (group-structure A-reuse: A slab staged once per kb,
// permutation applied at LDS-read address; B(r,kb) triple-buffered with
// counted vmcnt(2) + raw s_barrier, one barrier/iter).
// R4 (clean resubmit after container infra failure; kernel re-audited:
// uniform barriers, traced vmcnt ledger, exact staging coverage, no OOB):
// BK 64->32. LDS 76->39 KB => 4 blocks/CU (16 waves, 4 independent barrier
// domains) vs 2. R3 showed the stall is NOT load latency (counted vmcnt was
// ~neutral); it's issue/barrier bubbles at 2 waves/SIMD. m114: wave-level
// overlap across independent blocks fills those bubbles.
// BK=32 breaks the 8-chunk row swizzle (64B row = 16 banks -> 4-way).
// Pair-interleaved XOR layout instead: chunk (r,c) stored at 128B line
// (r>>1), slot (((r&1)<<2)|c) ^ ((r>>1)&7). Involution; linear LDS dest
// (global_load_lds-safe) with inverse perm folded into per-thread constant
// SOURCE offsets (guide §5 pre-swizzled-global pattern). B reads: exact
// 2-way (free, m136); permuted A reads ~2-way average (same as R1).
__launch_bounds__(256, 2)
__global__ void gemm_gc(const u16* __restrict__ xb, const u16* __restrict__ bt,
                        const float* __restrict__ bias, const int* __restrict__ pair_orbit,
                        float* __restrict__ out) {
  __shared__ __align__(16) u16 As[BM * BK];        // 12 KB, single buffer (per kb)
  __shared__ __align__(16) u16 Bs[3 * BN * BK];    // 24 KB, triple buffer (per r)
  __shared__ int jmap[GSZ * 25];                   // stride 25 (odd): conflict-free

  const int t   = threadIdx.x;
  const int gid = blockIdx.x;
  // XCD-aware: each XCD owns one 128-col B slice (3 MB -> L2-resident).
  const int xcd = gid & 7;
  const int n0  = (xcd & 3) * BN;
  const int m0  = ((gid >> 3) * 2 + (xcd >> 2)) * BM;

  // invert pair_orbit -> jmap[i][r] = j   (jmap[i*25 + r])
  for (int idx = t; idx < GSZ * NORB; idx += 256) {
    const int i = idx / 24;
    const int j = idx - i * 24;
    jmap[i * 25 + pair_orbit[idx]] = j;
  }

  // staging source offsets: dest 16B chunk d = it*256 + t at LDS line p=d>>3,
  // slot s=d&7; inverse perm: u = s ^ (p&7), source row = 2p + (u>>2),
  // source k-chunk = u&3.  (per-thread constants)
  int aOff[3], bOff[2];
#pragma unroll
  for (int it = 0; it < 3; ++it) {
    const int d = it * 256 + t, p = d >> 3, u = (d & 7) ^ (p & 7);
    aOff[it] = (m0 + 2 * p + (u >> 2)) * CIN + (u & 3) * 8;
  }
#pragma unroll
  for (int it = 0; it < 2; ++it) {
    const int d = it * 256 + t, p = d >> 3, u = (d & 7) ^ (p & 7);
    bOff[it] = (n0 + 2 * p + (u >> 2)) * K_DIM + (u & 3) * 8;
  }
  u16* aDst = (u16*)As + t * 8;
  u16* bDst = (u16*)Bs + t * 8;

  auto stage_a = [&](int kb) {
#pragma unroll
    for (int it = 0; it < 3; ++it)
      __builtin_amdgcn_global_load_lds(
          (__attribute__((address_space(1))) void*)(xb + aOff[it] + kb * 32),
          (__attribute__((address_space(3))) void*)(aDst + it * 2048), 16, 0, 0);
  };
  auto stage_b = [&](int kb, int r, int buf) {
#pragma unroll
    for (int it = 0; it < 2; ++it)
      __builtin_amdgcn_global_load_lds(
          (__attribute__((address_space(1))) void*)(bt + bOff[it] + r * 512 + kb * 32),
          (__attribute__((address_space(3))) void*)(bDst + buf * 4096 + it * 2048), 16, 0, 0);
  };

  // 4 waves, 2M x 2N, per-wave 96x64 output (6 x 4 fragments of 16x16)
  const int w    = t >> 6;
  const int lane = t & 63;
  const int lm   = lane & 15;
  const int q    = lane >> 4;      // k-chunk 0..3 (BK=32: one MFMA per frag pair)
  const int mw   = (w >> 1) * 96;
  const int nw   = (w & 1) * 64;

  int b24[6], i25[6];
#pragma unroll
  for (int f = 0; f < 6; ++f) {
    const int tr = mw + f * 16 + lm;   // tile row this lane reads for frag f
    const int b  = tr / 24;
    b24[f] = b * 24;
    i25[f] = (tr - b * 24) * 25;
  }
  // B read bases, hoisted (B rows linear): elem = (R>>1)*64 + slot*8
  int baseB[4];
#pragma unroll
  for (int nf = 0; nf < 4; ++nf) {
    const int R  = nw + nf * 16 + lm;
    const int Rh = R >> 1;
    const int s  = (((R & 1) << 2) | q) ^ (Rh & 7);
    baseB[nf] = Rh * 64 + s * 8;
  }

  f32x4 acc[6][4];
#pragma unroll
  for (int i = 0; i < 6; ++i)
#pragma unroll
    for (int j = 0; j < 4; ++j)
      acc[i][j] = (f32x4){0.f, 0.f, 0.f, 0.f};

  // prologue: A(0) + B(0)->buf0 drained; B(1)->buf1 in flight (2 loads)
  stage_a(0);
  stage_b(0, 0, 0);
  __syncthreads();                 // full drain: jmap + A(0) + B(0) ready
  stage_b(0, 1, 1);

  int rowC[6];                     // permuted A rows for current r
#pragma unroll
  for (int f = 0; f < 6; ++f) rowC[f] = b24[f] + jmap[i25[f]];   // r = 0

  int cur = 0, w2 = 2;             // read buf = tt%3, write buf = (tt+2)%3
  int r2 = 2, kb2 = 0;             // (tt+2) -> (kb2, r2)
  int rr = 0, kb = 0;              // current (kb, r)

#pragma unroll 1
  for (int tt = 0; tt < 384; ++tt) {
    // B(tt) landed (own-wave vmcnt); barrier publishes all waves' writes and
    // confirms everyone finished reading the buffer staged into below.
    if (tt < 383) asm volatile("s_waitcnt vmcnt(2)" ::: "memory");
    else          asm volatile("s_waitcnt vmcnt(0)" ::: "memory");
    __builtin_amdgcn_s_barrier();
    __builtin_amdgcn_sched_barrier(0);

    const bool bnd = (rr == 23);
    if (!bnd && tt < 382) stage_b(kb2, r2, w2);   // B(tt+2) -> buf (tt+2)%3

    // A read addresses (pair-interleaved layout, keyed on PERMUTED row)
    int c0[6];
#pragma unroll
    for (int f = 0; f < 6; ++f) {
      const int R  = rowC[f];
      const int Rh = R >> 1;
      const int s  = (((R & 1) << 2) | q) ^ (Rh & 7);
      c0[f] = Rh * 64 + s * 8;
    }

    // prefetch next-r permuted rows (hides jmap ds_read under MFMA cluster)
    int rowN[6];
    const int rn = bnd ? 0 : (rr + 1);
#pragma unroll
    for (int f = 0; f < 6; ++f) rowN[f] = b24[f] + jmap[i25[f] + rn];

    const int soff = cur * 4096;
    bf16x8 av[6], bv[4];
#pragma unroll
    for (int nf = 0; nf < 4; ++nf)
      bv[nf] = *(const bf16x8*)(Bs + soff + baseB[nf]);
#pragma unroll
    for (int f = 0; f < 6; ++f)
      av[f] = *(const bf16x8*)(As + c0[f]);
    __builtin_amdgcn_s_setprio(1);
#pragma unroll
    for (int mf = 0; mf < 6; ++mf)
#pragma unroll
      for (int nf = 0; nf < 4; ++nf)
        acc[mf][nf] = __builtin_amdgcn_mfma_f32_16x16x32_bf16(av[mf], bv[nf], acc[mf][nf], 0, 0, 0);
    __builtin_amdgcn_s_setprio(0);

#pragma unroll
    for (int f = 0; f < 6; ++f) rowC[f] = rowN[f];

    if (bnd && kb < 15) {
      // all waves done reading As for this kb; restage A then B so the
      // uniform vmcnt(2) next iter covers both (A issued before B(tt+2)).
      __builtin_amdgcn_s_barrier();
      __builtin_amdgcn_sched_barrier(0);
      stage_a(kb + 1);
      stage_b(kb2, r2, w2);              // (kb2,r2) = (kb+1, 1) here
    }

    cur = (cur == 2) ? 0 : cur + 1;
    w2  = (w2 == 2) ? 0 : w2 + 1;
    if (++r2 == 24) { r2 = 0; ++kb2; }
    if (++rr == 24) { rr = 0; ++kb; }
  }

  // epilogue: D row = q*4+e (m), col = lm (n); add bias[o=col]
#pragma unroll
  for (int nf = 0; nf < 4; ++nf) {
    const int col = n0 + nw + nf * 16 + lm;
    const float bv = bias[col];
#pragma unroll
    for (int mf = 0; mf < 6; ++mf) {
      const int mrow = m0 + mw + mf * 16 + q * 4;
#pragma unroll
      for (int e = 0; e < 4; ++e)
        out[(size_t)(mrow + e) * N_DIM + col] = acc[mf][nf][e] + bv;
    }
  }
}

extern "C" void kernel_launch(void* const* d_in, const int* in_sizes, int n_in,
                              void* d_out, int out_size, void* d_ws, size_t ws_size,
                              hipStream_t stream) {
  (void)in_sizes; (void)n_in; (void)out_size; (void)ws_size;
  const float* x    = (const float*)d_in[0];
  const float* wgt  = (const float*)d_in[1];
  const float* bias = (const float*)d_in[2];
  const int*   po   = (const int*)d_in[3];
  float* out = (float*)d_out;

  u16* xb = (u16*)d_ws;                       // 25,165,824 elems = 50.3 MB
  u16* bt = xb + (size_t)M_DIM * CIN;         // 512*12288 elems = 12.6 MB

  const int nx4 = (BATCH * GSZ * CIN) / 4;
  convert_x<<<nx4 / 1024, 256, 0, stream>>>(x, xb, nx4);
  build_bt<<<COUT, 256, 0, stream>>>(wgt, bt);

  const int grid = (M_DIM / BM) * (N_DIM / BN);  // 256*4 = 1024 = 4 blocks/CU, no tail
  gemm_gc<<<grid, 256, 0, stream>>>(xb, bt, bias, po, out);
}

// Round 6
// 670.298 us; speedup vs baseline: 1.1122x; 1.1122x over previous
//
#include <hip/hip_runtime.h>

#define BATCH 2048
#define CIN   512
#define COUT  512
#define GSZ   24
#define NORB  24
#define M_DIM (BATCH*GSZ)   // 49152
#define K_DIM (GSZ*CIN)     // 12288
#define N_DIM COUT          // 512
#define BM 192              // = 8 whole batches -> batch-aligned tiles
#define BN 128
#define BK 64               // R6: reverted to 64 (R5: BK=32 regressed; occupancy is capped at 2 blocks/CU regardless of LDS)

typedef __bf16 bf16x8 __attribute__((ext_vector_type(8)));
typedef float  f32x4  __attribute__((ext_vector_type(4)));
typedef unsigned short u16;

__device__ __forceinline__ u16 f2bf(float f) {
  union { float f; unsigned u; } v; v.f = f;
  unsigned u = v.u;
  return (u16)((u + 0x7fffu + ((u >> 16) & 1u)) >> 16);  // RNE
}

// ---- pre-pass 1: x fp32 -> bf16 (coalesced both ways, 4 float4/thread) ----
__global__ void convert_x(const float* __restrict__ x, u16* __restrict__ xb, int n4) {
  const int base = blockIdx.x * 1024 + threadIdx.x;
#pragma unroll
  for (int i = 0; i < 4; ++i) {
    const int t = base + i * 256;
    if (t >= n4) return;
    const float4 v = *(const float4*)(x + (size_t)t * 4);
    ushort4 o;
    o.x = f2bf(v.x); o.y = f2bf(v.y); o.z = f2bf(v.z); o.w = f2bf(v.w);
    *(ushort4*)(xb + (size_t)t * 4) = o;
  }
}

// ---- pre-pass 2: weight (O,C,R) fp32 -> Bt[o][r*512+c] bf16 ----
#define TROW 520
__global__ void build_bt(const float* __restrict__ w, u16* __restrict__ bt) {
  __shared__ __align__(16) u16 lds[NORB * TROW];
  const int o = blockIdx.x;
  const int t = threadIdx.x;
  const float* wo = w + (size_t)o * K_DIM;
#pragma unroll
  for (int it = 0; it < 12; ++it) {
    const int idx = it * 256 + t;
    const float4 v = *(const float4*)(wo + idx * 4);
    const int k0 = idx * 4;
#pragma unroll
    for (int e = 0; e < 4; ++e) {
      const int k = k0 + e;
      const int c = k / 24;
      const int r = k - c * 24;
      lds[r * TROW + c] = f2bf(e == 0 ? v.x : e == 1 ? v.y : e == 2 ? v.z : v.w);
    }
  }
  __syncthreads();
  u16* bo = bt + (size_t)o * K_DIM;
#pragma unroll
  for (int it = 0; it < 6; ++it) {
    const int eidx = it * 256 + t;
    const int base = eidx * 8;
    const int r = base >> 9;
    const int c0 = base & 511;
    const uint4 v = *(const uint4*)(lds + r * TROW + c0);
    *(uint4*)(bo + base) = v;
  }
}

// ---- main GEMM: C[M,512] = A[M,K] * B[K,512] + bias ----
// Base: R1/R3 structure (group-structure A-reuse: A slab once per kb,
// permutation at LDS-read; B(r,kb) triple-buffered; BK=64; 16x16x32 MFMA).
// R6: REGISTER-LEVEL CROSS-BARRIER PIPELINE. Ledger change: B(t+1) is
// landed+published at barrier t (everything drained at top; loads were
// issued a full iteration earlier so the drain is cheap, unlike m97's
// just-in-time drain). This makes buf (t+1)%3 readable DURING iter t, so
// each half-cluster's fragments are prefetched one phase ahead:
//   top: __syncthreads(); stage_b(t+2) -> buf (t+2)%3   [readers retired]
//   phase A: ds_read Q <- h1(t)   ; MFMA on P (zero lgkm wait at top)
//   phase B: ds_read P <- h0(t+1) from buf (t+1)%3 ; MFMA on Q
// MFMAs never wait on their own operand reads (reads hidden under the
// other cluster's 24 MFMAs). kb boundary: phase B skips A-prefetch, 2nd
// barrier, restage A; next iter is "cold" (reads P itself). 7 occurrences.
__launch_bounds__(256, 2)
__global__ void gemm_gc(const u16* __restrict__ xb, const u16* __restrict__ bt,
                        const float* __restrict__ bias, const int* __restrict__ pair_orbit,
                        float* __restrict__ out) {
  __shared__ __align__(16) u16 As[BM * BK];        // 24 KB, single buffer (per kb)
  __shared__ __align__(16) u16 Bs[3 * BN * BK];    // 48 KB, triple buffer (per r)
  __shared__ int jmap[GSZ * 25];                   // stride 25 (odd): conflict-free

  const int t   = threadIdx.x;
  const int gid = blockIdx.x;
  // XCD-aware: each XCD owns one 128-col B slice (3 MB -> L2-resident).
  const int xcd = gid & 7;
  const int n0  = (xcd & 3) * BN;
  const int m0  = ((gid >> 3) * 2 + (xcd >> 2)) * BM;

  // invert pair_orbit -> jmap[i][r] = j   (jmap[i*25 + r])
  for (int idx = t; idx < GSZ * NORB; idx += 256) {
    const int i = idx / 24;
    const int j = idx - i * 24;
    jmap[i * 25 + pair_orbit[idx]] = j;
  }

  // staging: thread t owns 16B chunk; row = t>>3, slot = t&7 holds source
  // chunk (t&7)^(row&7)  => read of chunk c at row r lives at slot c^(r&7).
  const int tr0 = t >> 3;
  const int kcg = ((t & 7) ^ (tr0 & 7)) * 8;
  const u16* aSrc = xb + (size_t)(m0 + tr0) * CIN + kcg;
  const u16* bSrc = bt + (size_t)(n0 + tr0) * K_DIM + kcg;
  u16* aDst = (u16*)As + t * 8;
  u16* bDst = (u16*)Bs + t * 8;

  auto stage_a = [&](int kb) {
#pragma unroll
    for (int it = 0; it < 6; ++it)
      __builtin_amdgcn_global_load_lds(
          (__attribute__((address_space(1))) void*)(aSrc + (size_t)it * 32 * CIN + kb * 64),
          (__attribute__((address_space(3))) void*)(aDst + it * 2048), 16, 0, 0);
  };
  auto stage_b = [&](int kb, int r, int soffElems) {
#pragma unroll
    for (int it = 0; it < 4; ++it)
      __builtin_amdgcn_global_load_lds(
          (__attribute__((address_space(1))) void*)(bSrc + (size_t)it * 32 * K_DIM + r * 512 + kb * 64),
          (__attribute__((address_space(3))) void*)(bDst + soffElems + it * 2048), 16, 0, 0);
  };

  // 4 waves, 2M x 2N, per-wave 96x64 output (6 x 4 fragments of 16x16)
  const int w    = t >> 6;
  const int lane = t & 63;
  const int lm   = lane & 15;
  const int q    = lane >> 4;
  const int mw   = (w >> 1) * 96;
  const int nw   = (w & 1) * 64;
  const int q8   = q << 3;

  int b24[6], i25[6];
#pragma unroll
  for (int f = 0; f < 6; ++f) {
    const int tr = mw + f * 16 + lm;   // tile row this lane reads for frag f
    const int b  = tr / 24;
    b24[f] = b * 24;
    i25[f] = (tr - b * 24) * 25;
  }
  // B addresses hoisted (B rows are NOT permuted); h1 adds ^32
  int baseB[4];
#pragma unroll
  for (int nf = 0; nf < 4; ++nf)
    baseB[nf] = (nw + lm + 16 * nf) * 64 + (q8 ^ ((lm & 7) << 3));

  f32x4 acc[6][4];
#pragma unroll
  for (int i = 0; i < 6; ++i)
#pragma unroll
    for (int j = 0; j < 4; ++j)
      acc[i][j] = (f32x4){0.f, 0.f, 0.f, 0.f};

  // prologue: A(0), B(0)->buf0, B(1)->buf1 all staged, then full drain.
  stage_a(0);
  stage_b(0, 0, 0);
  stage_b(0, 1, 8192);
  __syncthreads();                 // jmap + A(0) + B(0) + B(1) landed & visible

  int rowC[6], c0C[6];             // rows + A-read bases for current r
#pragma unroll
  for (int f = 0; f < 6; ++f) {
    rowC[f] = b24[f] + jmap[i25[f]];             // r = 0
    c0C[f] = rowC[f] * 64 + (q8 ^ ((rowC[f] & 7) << 3));
  }

  bf16x8 avP[6], bvP[4], avQ[6], bvQ[4];         // frag double-buffer (2 half-sets)

  int cur = 0, nxt = 1, w2 = 2;    // buf(t)%3, buf(t+1)%3, buf(t+2)%3
  int r2 = 2, kb2 = 0;             // (t+2) -> (kb2, r2)
  int rr = 0, kb = 0;              // current (kb, r)

#pragma unroll 1
  for (int tt = 0; tt < 192; ++tt) {
    // Drain everything (issued >= 1 full iter ago -> cheap) and publish:
    // B(t), B(t+1) visible; at cold iters also A(kb).
    __syncthreads();

    const bool bnd  = (rr == 23);
    if (tt < 190) stage_b(kb2, r2, w2 << 13);    // B(t+2) -> buf (t+2)%3 (readers retired)

    const int soffC = cur << 13;
    const int soffN = nxt << 13;

    if (rr == 0) {                 // cold iter: P (h0 of t) not preloaded
#pragma unroll
      for (int nf = 0; nf < 4; ++nf)
        bvP[nf] = *(const bf16x8*)(Bs + soffC + baseB[nf]);
#pragma unroll
      for (int f = 0; f < 6; ++f)
        avP[f] = *(const bf16x8*)(As + c0C[f]);
    }

    // ---- phase A: prefetch Q <- h1(t); MFMA on P ----
#pragma unroll
    for (int nf = 0; nf < 4; ++nf)
      bvQ[nf] = *(const bf16x8*)(Bs + soffC + (baseB[nf] ^ 32));
#pragma unroll
    for (int f = 0; f < 6; ++f)
      avQ[f] = *(const bf16x8*)(As + (c0C[f] ^ 32));
    __builtin_amdgcn_s_setprio(1);
#pragma unroll
    for (int mf = 0; mf < 6; ++mf)
#pragma unroll
      for (int nf = 0; nf < 4; ++nf)
        acc[mf][nf] = __builtin_amdgcn_mfma_f32_16x16x32_bf16(avP[mf], bvP[nf], acc[mf][nf], 0, 0, 0);
    __builtin_amdgcn_s_setprio(0);

    // rows/addresses for iter t+1 (jmap ds_read hidden under MFMA cluster)
    const int rn = bnd ? 0 : (rr + 1);
    int rowN[6], c0N[6];
#pragma unroll
    for (int f = 0; f < 6; ++f) {
      rowN[f] = b24[f] + jmap[i25[f] + rn];
      c0N[f] = rowN[f] * 64 + (q8 ^ ((rowN[f] & 7) << 3));
    }

    // ---- phase B: prefetch P <- h0(t+1) (A only if same kb); MFMA on Q ----
#pragma unroll
    for (int nf = 0; nf < 4; ++nf)
      bvP[nf] = *(const bf16x8*)(Bs + soffN + baseB[nf]);
    if (!bnd) {
#pragma unroll
      for (int f = 0; f < 6; ++f)
        avP[f] = *(const bf16x8*)(As + c0N[f]);
    }
    __builtin_amdgcn_s_setprio(1);
#pragma unroll
    for (int mf = 0; mf < 6; ++mf)
#pragma unroll
      for (int nf = 0; nf < 4; ++nf)
        acc[mf][nf] = __builtin_amdgcn_mfma_f32_16x16x32_bf16(avQ[mf], bvQ[nf], acc[mf][nf], 0, 0, 0);
    __builtin_amdgcn_s_setprio(0);

#pragma unroll
    for (int f = 0; f < 6; ++f) { rowC[f] = rowN[f]; c0C[f] = c0N[f]; }

    if (bnd && kb < 7) {
      __syncthreads();             // all waves done reading As(kb)
      stage_a(kb + 1);             // drained+published by next top barrier
    }

    // rotate buffer indices: (cur,nxt,w2) <- (nxt,w2,cur)
    const int tmp = cur; cur = nxt; nxt = w2; w2 = tmp;
    if (++r2 == 24) { r2 = 0; ++kb2; }
    if (++rr == 24) { rr = 0; ++kb; }
  }

  // epilogue: D row = q*4+e (m), col = lm (n); add bias[o=col]
#pragma unroll
  for (int nf = 0; nf < 4; ++nf) {
    const int col = n0 + nw + nf * 16 + lm;
    const float bv = bias[col];
#pragma unroll
    for (int mf = 0; mf < 6; ++mf) {
      const int mrow = m0 + mw + mf * 16 + q * 4;
#pragma unroll
      for (int e = 0; e < 4; ++e)
        out[(size_t)(mrow + e) * N_DIM + col] = acc[mf][nf][e] + bv;
    }
  }
}

extern "C" void kernel_launch(void* const* d_in, const int* in_sizes, int n_in,
                              void* d_out, int out_size, void* d_ws, size_t ws_size,
                              hipStream_t stream) {
  (void)in_sizes; (void)n_in; (void)out_size; (void)ws_size;
  const float* x    = (const float*)d_in[0];
  const float* wgt  = (const float*)d_in[1];
  const float* bias = (const float*)d_in[2];
  const int*   po   = (const int*)d_in[3];
  float* out = (float*)d_out;

  u16* xb = (u16*)d_ws;                       // 25,165,824 elems = 50.3 MB
  u16* bt = xb + (size_t)M_DIM * CIN;         // 512*12288 elems = 12.6 MB

  const int nx4 = (BATCH * GSZ * CIN) / 4;
  convert_x<<<nx4 / 1024, 256, 0, stream>>>(x, xb, nx4);
  build_bt<<<COUT, 256, 0, stream>>>(wgt, bt);

  const int grid = (M_DIM / BM) * (N_DIM / BN);  // 256*4 = 1024
  gemm_gc<<<grid, 256, 0, stream>>>(xb, bt, bias, po, out);
}